// Round 1
// baseline (13261.978 us; speedup 1.0000x reference)
//
#include <hip/hip_runtime.h>
#include <stdint.h>

// GRU fused persistent kernel, MI355X gfx950.
// B=64,T=512,DIN=DOUT=512, fp32 in/out. One persistent kernel:
//  - 4 batch-groups (M=16) x 32 WGs (j-slice 16) = 128 blocks (<=256 CUs, co-resident)
//  - per WG: 4 waves K-split (128 each), LDS reduction of partials
//  - weights as MFMA B-frags in registers (hi/lo bf16 split for U_* for precision)
//  - x-projections fused (X read once, loads issued before the h-spin)
//  - cross-WG h/r exchange via d_ws + agent-scope counters (+threadfence for XCD coherence)
// ws layout (floats): hbuf[2][4][16][512] | rbuf[4][16][512] | counters (u32, 128B strided)
// WAR safety: r(t+1) writes gated by h-sync(t) (all r(t) reads precede it);
// h parity buffer (t+2 overwrite gated by r-sync(t+1), all h(t) reads precede phase A(t) end).

#define GB    64
#define GT    512
#define GDIN  512
#define GDOUT 512
#define NGRP  4
#define NP    32
#define JS    16
#define KW    128
#define NWAVE 4

typedef __attribute__((ext_vector_type(8))) short bf16x8;
typedef __attribute__((ext_vector_type(4))) float f32x4;

__device__ __forceinline__ short f2bf(float f) {
  union { float f; uint32_t u; } v; v.f = f;
  uint32_t r = (v.u + 0x7FFFu + ((v.u >> 16) & 1u)) >> 16;  // RNE
  return (short)(uint16_t)r;
}
__device__ __forceinline__ float bf2f(short s) {
  union { uint32_t u; float f; } v; v.u = ((uint32_t)(uint16_t)s) << 16;
  return v.f;
}

__global__ __launch_bounds__(256, 1)
void gru_fused(const float* __restrict__ X, const int* __restrict__ mask,
               const float* __restrict__ Wz, const float* __restrict__ Uz,
               const float* __restrict__ bz,
               const float* __restrict__ Wr, const float* __restrict__ Ur,
               const float* __restrict__ br,
               const float* __restrict__ Wh, const float* __restrict__ Uh,
               const float* __restrict__ bh,
               float* __restrict__ out, float* __restrict__ ws)
{
  const int p    = blockIdx.x;
  const int g    = p & (NGRP - 1);     // group = blockIdx%4 -> 2 XCDs/group locality
  const int pg   = p >> 2;             // 0..31: j-slice index within group
  const int jb   = pg * JS;
  const int tid  = threadIdx.x;
  const int wv   = tid >> 6;
  const int lane = tid & 63;
  const int col  = lane & 15;          // MFMA: A row m / D col n
  const int quad = lane >> 4;
  const int kb   = wv * KW;            // wave's K offset

  float* hbuf = ws;                                // [2][NGRP][16][GDOUT]
  float* rbuf = ws + 2 * NGRP * 16 * GDOUT;        // [NGRP][16][GDOUT]
  uint32_t* cnts = (uint32_t*)(rbuf + NGRP * 16 * GDOUT);
  uint32_t* rcnt = cnts + (2 * g + 0) * 32;        // 128B strided, no false sharing
  uint32_t* hcnt = cnts + (2 * g + 1) * 32;

  __shared__ __align__(16) float scratch[NWAVE][2][320]; // [col*20+row] pad: 2-way banks

  // ---------- one-time: weight B-fragments into registers ----------
  // B-frag (16x16x32): lane holds M[k][jb+col], k = kb + c*32 + quad*8 + i
  bf16x8 uzh[4], uzl[4], urh[4], url[4], uhh[4], uhl[4];
  bf16x8 wzf[4], wrf[4], whf[4];
#pragma unroll
  for (int c = 0; c < 4; ++c) {
    const int k0 = kb + c * 32 + quad * 8;
    bf16x8 t_uzh, t_uzl, t_urh, t_url, t_uhh, t_uhl, t_wz, t_wr, t_wh;
#pragma unroll
    for (int i = 0; i < 8; ++i) {
      const int idx = (k0 + i) * GDOUT + jb + col;
      float u; short hi;
      u = Uz[idx]; hi = f2bf(u); t_uzh[i] = hi; t_uzl[i] = f2bf(u - bf2f(hi));
      u = Ur[idx]; hi = f2bf(u); t_urh[i] = hi; t_url[i] = f2bf(u - bf2f(hi));
      u = Uh[idx]; hi = f2bf(u); t_uhh[i] = hi; t_uhl[i] = f2bf(u - bf2f(hi));
      t_wz[i] = f2bf(Wz[idx]);
      t_wr[i] = f2bf(Wr[idx]);
      t_wh[i] = f2bf(Wh[idx]);
    }
    uzh[c] = t_uzh; uzl[c] = t_uzl; urh[c] = t_urh; url[c] = t_url;
    uhh[c] = t_uhh; uhl[c] = t_uhl; wzf[c] = t_wz; wrf[c] = t_wr; whf[c] = t_wh;
  }
  const float bzv = bz[jb + col];
  const float brv = br[jb + col];
  const float bhv = bh[jb + col];

  const int sco = col * 20 + quad * 4;

  for (int t = 0; t < GT; ++t) {
    // ---- X fragments for step t (independent of sync: issue before h-spin) ----
    bf16x8 xa[4];
#pragma unroll
    for (int c = 0; c < 4; ++c) {
      const int k0 = kb + c * 32 + quad * 8;
      const float* xp = X + ((size_t)(16 * g + col) * GT + t) * GDIN + k0;
      f32x4 x0 = *(const f32x4*)xp;
      f32x4 x1 = *(const f32x4*)(xp + 4);
      bf16x8 xf;
#pragma unroll
      for (int i = 0; i < 4; ++i) { xf[i] = f2bf(x0[i]); xf[i + 4] = f2bf(x1[i]); }
      xa[c] = xf;
    }

    // ---- wait for h(t) (all P WGs of group finished step t-1) ----
    if (lane == 0) {
      const uint32_t tgt = (uint32_t)(NP * t);
      int it = 0;
      while (__hip_atomic_load(hcnt, __ATOMIC_RELAXED, __HIP_MEMORY_SCOPE_AGENT) < tgt) {
        __builtin_amdgcn_s_sleep(1);
        if (++it > 100000) break;   // bounded spin: deadlock -> wrong result, not hang
      }
    }
    __threadfence();   // acquire: make peers' h stores visible (cross-XCD L2 inv)

    const float* hsrc = hbuf + ((size_t)(t & 1) * NGRP + g) * 16 * GDOUT;
    float*       hdst = hbuf + ((size_t)((t + 1) & 1) * NGRP + g) * 16 * GDOUT;

    // ---- h A-fragments: keep f32 copy (for r*h), plus bf16 hi/lo split ----
    f32x4 hf0[4], hf1[4];
    bf16x8 hhi[4], hlo[4];
#pragma unroll
    for (int c = 0; c < 4; ++c) {
      const int k0 = kb + c * 32 + quad * 8;
      const float* hp = hsrc + col * GDOUT + k0;
      hf0[c] = *(const f32x4*)hp;
      hf1[c] = *(const f32x4*)(hp + 4);
      bf16x8 th, tl;
#pragma unroll
      for (int i = 0; i < 4; ++i) {
        short a = f2bf(hf0[c][i]); th[i] = a;     tl[i] = f2bf(hf0[c][i] - bf2f(a));
        short b = f2bf(hf1[c][i]); th[i + 4] = b; tl[i + 4] = f2bf(hf1[c][i] - bf2f(b));
      }
      hhi[c] = th; hlo[c] = tl;
    }

    // ---- phase A MFMAs: az = h@Uz + X@Wz (split), ar likewise, ah = X@Wh ----
    f32x4 az = {0.f, 0.f, 0.f, 0.f}, ar = {0.f, 0.f, 0.f, 0.f}, ah = {0.f, 0.f, 0.f, 0.f};
#pragma unroll
    for (int c = 0; c < 4; ++c) {
      az = __builtin_amdgcn_mfma_f32_16x16x32_bf16(hhi[c], uzh[c], az, 0, 0, 0);
      az = __builtin_amdgcn_mfma_f32_16x16x32_bf16(hlo[c], uzh[c], az, 0, 0, 0);
      az = __builtin_amdgcn_mfma_f32_16x16x32_bf16(hhi[c], uzl[c], az, 0, 0, 0);
      az = __builtin_amdgcn_mfma_f32_16x16x32_bf16(xa[c],  wzf[c], az, 0, 0, 0);
      ar = __builtin_amdgcn_mfma_f32_16x16x32_bf16(hhi[c], urh[c], ar, 0, 0, 0);
      ar = __builtin_amdgcn_mfma_f32_16x16x32_bf16(hlo[c], urh[c], ar, 0, 0, 0);
      ar = __builtin_amdgcn_mfma_f32_16x16x32_bf16(hhi[c], url[c], ar, 0, 0, 0);
      ar = __builtin_amdgcn_mfma_f32_16x16x32_bf16(xa[c],  wrf[c], ar, 0, 0, 0);
      ah = __builtin_amdgcn_mfma_f32_16x16x32_bf16(xa[c],  whf[c], ah, 0, 0, 0);
    }

    // ---- reduce z,r partials across the 4 K-split waves ----
    __syncthreads();                               // scratch free (prev iter reads done)
    *(f32x4*)&scratch[wv][0][sco] = az;
    *(f32x4*)&scratch[wv][1][sco] = ar;
    __syncthreads();
    f32x4 zs = {0, 0, 0, 0}, rs = {0, 0, 0, 0};
#pragma unroll
    for (int w2 = 0; w2 < NWAVE; ++w2) {
      zs += *(const f32x4*)&scratch[w2][0][sco];
      rs += *(const f32x4*)&scratch[w2][1][sco];
    }

    float zv[4], rv[4];
#pragma unroll
    for (int i = 0; i < 4; ++i) {
      zv[i] = 1.f / (1.f + __expf(-(zs[i] + bzv)));
      rv[i] = 1.f / (1.f + __expf(-(rs[i] + brv)));
    }

    float hold[4]; int mk[4];
    if (wv == 0) {
      float* rdst = rbuf + (size_t)g * 16 * GDOUT;
#pragma unroll
      for (int i = 0; i < 4; ++i) {
        const int row = quad * 4 + i;              // D: row=quad*4+i (batch), col=n
        rdst[row * GDOUT + jb + col] = rv[i];
        hold[i] = hsrc[row * GDOUT + jb + col];    // prefetch epilogue operands
        mk[i] = mask[(16 * g + row) * GT + t];
      }
    }
    __syncthreads();                               // scratch reads done (WAR for phase B)
    if (tid == 0) { __threadfence(); atomicAdd(rcnt, 1u); }   // release r-slice

    // ---- wait for full r(t) ----
    if (lane == 0) {
      const uint32_t tgt = (uint32_t)(NP * (t + 1));
      int it = 0;
      while (__hip_atomic_load(rcnt, __ATOMIC_RELAXED, __HIP_MEMORY_SCOPE_AGENT) < tgt) {
        __builtin_amdgcn_s_sleep(1);
        if (++it > 100000) break;
      }
    }
    __threadfence();

    // ---- phase B: ah += (r .* h) @ Uh  (hi/lo split) ----
    const float* rsrc = rbuf + (size_t)g * 16 * GDOUT;
#pragma unroll
    for (int c = 0; c < 4; ++c) {
      const int k0 = kb + c * 32 + quad * 8;
      const float* rp = rsrc + col * GDOUT + k0;
      f32x4 r0 = *(const f32x4*)rp;
      f32x4 r1 = *(const f32x4*)(rp + 4);
      bf16x8 th, tl;
#pragma unroll
      for (int i = 0; i < 4; ++i) {
        float v0 = r0[i] * hf0[c][i];
        float v1 = r1[i] * hf1[c][i];
        short a = f2bf(v0); th[i] = a;     tl[i] = f2bf(v0 - bf2f(a));
        short b = f2bf(v1); th[i + 4] = b; tl[i + 4] = f2bf(v1 - bf2f(b));
      }
      ah = __builtin_amdgcn_mfma_f32_16x16x32_bf16(th, uhh[c], ah, 0, 0, 0);
      ah = __builtin_amdgcn_mfma_f32_16x16x32_bf16(tl, uhh[c], ah, 0, 0, 0);
      ah = __builtin_amdgcn_mfma_f32_16x16x32_bf16(th, uhl[c], ah, 0, 0, 0);
    }

    *(f32x4*)&scratch[wv][0][sco] = ah;
    __syncthreads();
    if (wv == 0) {
      f32x4 hs = {0, 0, 0, 0};
#pragma unroll
      for (int w2 = 0; w2 < NWAVE; ++w2)
        hs += *(const f32x4*)&scratch[w2][0][sco];
#pragma unroll
      for (int i = 0; i < 4; ++i) {
        const int row = quad * 4 + i;
        const float pre = hs[i] + bhv;
        const float e = __expf(2.f * pre);         // tanh, saturation-safe
        const float hh = 1.f - 2.f / (e + 1.f);
        float hn = zv[i] * hold[i] + (1.f - zv[i]) * hh;
        hn = (mk[i] > 0) ? hn : hold[i];
        hdst[row * GDOUT + jb + col] = hn;
        if (t == GT - 1) out[(16 * g + row) * GDOUT + jb + col] = hn;
      }
    }
    if (tid == 0) { __threadfence(); atomicAdd(hcnt, 1u); }   // release h(t+1)
  }
}

extern "C" void kernel_launch(void* const* d_in, const int* in_sizes, int n_in,
                              void* d_out, int out_size, void* d_ws, size_t ws_size,
                              hipStream_t stream) {
  const float* X  = (const float*)d_in[0];
  const int* mask = (const int*)d_in[1];
  const float* Wz = (const float*)d_in[2];
  const float* Uz = (const float*)d_in[3];
  const float* bz = (const float*)d_in[4];
  const float* Wr = (const float*)d_in[5];
  const float* Ur = (const float*)d_in[6];
  const float* br = (const float*)d_in[7];
  const float* Wh = (const float*)d_in[8];
  const float* Uh = (const float*)d_in[9];
  const float* bh = (const float*)d_in[10];

  // zero h0, r, and sync counters (ws is poisoned 0xAA before every launch)
  const size_t initBytes = (size_t)(2 * NGRP + NGRP) * 16 * GDOUT * 4 + 4096;
  hipMemsetAsync(d_ws, 0, initBytes, stream);

  hipLaunchKernelGGL(gru_fused, dim3(NGRP * NP), dim3(256), 0, stream,
                     X, mask, Wz, Uz, bz, Wr, Ur, br, Wh, Uh, bh,
                     (float*)d_out, (float*)d_ws);
}

// Round 2
// 4505.342 us; speedup vs baseline: 2.9436x; 2.9436x over previous
//
#include <hip/hip_runtime.h>
#include <stdint.h>

// GRU fused persistent kernel, MI355X gfx950 — round 2.
// Round-1 lesson: __threadfence() on multi-XCD gfx950 = full L2 wbinv per call
// (4/step/WG = 262k flushes -> 13.3ms, WRITE_SIZE 135MB). This round: NO cache
// flushes. All cross-WG exchanged data (hbuf/rbuf) uses sc0 sc1 loads/stores
// (bypass L1+L2, coherent at L3); release = s_waitcnt vmcnt(0) + relaxed
// agent-scope atomic add (global_atomic_add sc1); acquire = relaxed agent poll.
// Exchanged lines never enter L1/L2 -> no invalidate needed, L3 stays hot.
//
// Structure (unchanged): 4 batch-groups (M=16) x 32 WGs (j-slice 16) = 128
// blocks co-resident; per WG 4 waves K-split 128 + LDS reduce; weights as
// register B-frags (hi/lo bf16 split on U_* for fp32-grade recurrence);
// X projections fused, X read once.
// ws: hbuf[2][4][16][512] f32 | rbuf[4][16][512] f32 | counters u32 128B-strided.
// WAR safety: r(t+1) writes gated by h-sync(t+1); h parity-buffer overwrite
// (t+2) gated by r-sync chain — all reads provably precede (see r1 analysis).

#define GT    512
#define GDIN  512
#define GDOUT 512
#define NGRP  4
#define NP    32
#define JS    16
#define KW    128
#define NWAVE 4

typedef __attribute__((ext_vector_type(8))) short bf16x8;
typedef __attribute__((ext_vector_type(4))) float f32x4;

__device__ __forceinline__ short f2bf(float f) {
  union { float f; uint32_t u; } v; v.f = f;
  uint32_t r = (v.u + 0x7FFFu + ((v.u >> 16) & 1u)) >> 16;  // RNE
  return (short)(uint16_t)r;
}
__device__ __forceinline__ float bf2f(short s) {
  union { uint32_t u; float f; } v; v.u = ((uint32_t)(uint16_t)s) << 16;
  return v.f;
}

// coherent (L3-level) scalar store, no cache pollution, no fence
__device__ __forceinline__ void cstore1(float* p, float v) {
  asm volatile("global_store_dword %0, %1, off sc0 sc1" :: "v"(p), "v"(v) : "memory");
}
// wave-level drain of outstanding vector-memory ops (release half)
__device__ __forceinline__ void vm_drain() {
  asm volatile("s_waitcnt vmcnt(0)" ::: "memory");
}

// 8x dwordx4 coherent loads from base + {c*128 + 0/16 bytes}, one waitcnt.
// Loads the wave's 16x(32 floats) A-operand slab: d0[c]=floats[c*32+0..3+quad*8],
// d1[c]=floats[c*32+4..7+quad*8] (quad*8 folded into base).
__device__ __forceinline__ void cload_slab(const float* base, f32x4 d0[4], f32x4 d1[4]) {
  asm volatile(
    "global_load_dwordx4 %0, %8, off sc0 sc1\n\t"
    "global_load_dwordx4 %1, %8, off offset:16 sc0 sc1\n\t"
    "global_load_dwordx4 %2, %8, off offset:128 sc0 sc1\n\t"
    "global_load_dwordx4 %3, %8, off offset:144 sc0 sc1\n\t"
    "global_load_dwordx4 %4, %8, off offset:256 sc0 sc1\n\t"
    "global_load_dwordx4 %5, %8, off offset:272 sc0 sc1\n\t"
    "global_load_dwordx4 %6, %8, off offset:384 sc0 sc1\n\t"
    "global_load_dwordx4 %7, %8, off offset:400 sc0 sc1\n\t"
    "s_waitcnt vmcnt(0)"
    : "=&v"(d0[0]), "=&v"(d1[0]), "=&v"(d0[1]), "=&v"(d1[1]),
      "=&v"(d0[2]), "=&v"(d1[2]), "=&v"(d0[3]), "=&v"(d1[3])
    : "v"(base)
    : "memory");
}

__global__ __launch_bounds__(256, 1)
void gru_fused(const float* __restrict__ X, const int* __restrict__ mask,
               const float* __restrict__ Wz, const float* __restrict__ Uz,
               const float* __restrict__ bz,
               const float* __restrict__ Wr, const float* __restrict__ Ur,
               const float* __restrict__ br,
               const float* __restrict__ Wh, const float* __restrict__ Uh,
               const float* __restrict__ bh,
               float* __restrict__ out, float* __restrict__ ws)
{
  const int p    = blockIdx.x;
  const int g    = p & (NGRP - 1);
  const int pg   = p >> 2;
  const int jb   = pg * JS;
  const int tid  = threadIdx.x;
  const int wv   = tid >> 6;
  const int lane = tid & 63;
  const int col  = lane & 15;
  const int quad = lane >> 4;
  const int kb   = wv * KW;

  float* hbuf = ws;                                // [2][NGRP][16][GDOUT]
  float* rbuf = ws + 2 * NGRP * 16 * GDOUT;        // [NGRP][16][GDOUT]
  uint32_t* cnts = (uint32_t*)(rbuf + NGRP * 16 * GDOUT);
  uint32_t* rcnt = cnts + (2 * g + 0) * 32;
  uint32_t* hcnt = cnts + (2 * g + 1) * 32;

  __shared__ __align__(16) float scratch[NWAVE][2][320];

  // ---------- one-time: weight B-fragments into registers ----------
  bf16x8 uzh[4], uzl[4], urh[4], url[4], uhh[4], uhl[4];
  bf16x8 wzf[4], wrf[4], whf[4];
#pragma unroll
  for (int c = 0; c < 4; ++c) {
    const int k0 = kb + c * 32 + quad * 8;
    bf16x8 t_uzh, t_uzl, t_urh, t_url, t_uhh, t_uhl, t_wz, t_wr, t_wh;
#pragma unroll
    for (int i = 0; i < 8; ++i) {
      const int idx = (k0 + i) * GDOUT + jb + col;
      float u; short hi;
      u = Uz[idx]; hi = f2bf(u); t_uzh[i] = hi; t_uzl[i] = f2bf(u - bf2f(hi));
      u = Ur[idx]; hi = f2bf(u); t_urh[i] = hi; t_url[i] = f2bf(u - bf2f(hi));
      u = Uh[idx]; hi = f2bf(u); t_uhh[i] = hi; t_uhl[i] = f2bf(u - bf2f(hi));
      t_wz[i] = f2bf(Wz[idx]);
      t_wr[i] = f2bf(Wr[idx]);
      t_wh[i] = f2bf(Wh[idx]);
    }
    uzh[c] = t_uzh; uzl[c] = t_uzl; urh[c] = t_urh; url[c] = t_url;
    uhh[c] = t_uhh; uhl[c] = t_uhl; wzf[c] = t_wz; wrf[c] = t_wr; whf[c] = t_wh;
  }
  const float bzv = bz[jb + col];
  const float brv = br[jb + col];
  const float bhv = bh[jb + col];

  const int sco = col * 20 + quad * 4;

  // wv0 epilogue state: my 4 h-values (rows quad*4+i, column jb+col) — exactly
  // the values I stored last step, so no re-read of hsrc in the epilogue.
  float hreg[4] = {0.f, 0.f, 0.f, 0.f};

  for (int t = 0; t < GT; ++t) {
    // ---- pre-spin: X fragments + mask for step t (sync-independent) ----
    bf16x8 xa[4];
#pragma unroll
    for (int c = 0; c < 4; ++c) {
      const int k0 = kb + c * 32 + quad * 8;
      const float* xp = X + ((size_t)(16 * g + col) * GT + t) * GDIN + k0;
      f32x4 x0 = *(const f32x4*)xp;
      f32x4 x1 = *(const f32x4*)(xp + 4);
      bf16x8 xf;
#pragma unroll
      for (int i = 0; i < 4; ++i) { xf[i] = f2bf(x0[i]); xf[i + 4] = f2bf(x1[i]); }
      xa[c] = xf;
    }
    int mk[4];
    if (wv == 0) {
#pragma unroll
      for (int i = 0; i < 4; ++i)
        mk[i] = mask[(16 * g + quad * 4 + i) * GT + t];
    }

    // ---- wait for h(t): whole wave parks while lane 0's exec-masked spin runs ----
    if (lane == 0) {
      const uint32_t tgt = (uint32_t)(NP * t);
      int it = 0;
      while (__hip_atomic_load(hcnt, __ATOMIC_RELAXED, __HIP_MEMORY_SCOPE_AGENT) < tgt) {
        __builtin_amdgcn_s_sleep(1);
        if (++it > 200000) break;   // bounded: deadlock -> wrong answer, not hang
      }
    }
    asm volatile("" ::: "memory");  // compiler barrier (no HW fence needed: data is L2-bypassed)

    const float* hsrc = hbuf + ((size_t)(t & 1) * NGRP + g) * 16 * GDOUT;
    float*       hdst = hbuf + ((size_t)((t + 1) & 1) * NGRP + g) * 16 * GDOUT;

    // ---- h A-slab: 8 pipelined coherent 16B loads, then bf16 hi/lo split ----
    f32x4 hf0[4], hf1[4];
    cload_slab(hsrc + col * GDOUT + kb + quad * 8, hf0, hf1);
    bf16x8 hhi[4], hlo[4];
#pragma unroll
    for (int c = 0; c < 4; ++c) {
      bf16x8 th, tl;
#pragma unroll
      for (int i = 0; i < 4; ++i) {
        short a = f2bf(hf0[c][i]); th[i] = a;     tl[i] = f2bf(hf0[c][i] - bf2f(a));
        short b = f2bf(hf1[c][i]); th[i + 4] = b; tl[i + 4] = f2bf(hf1[c][i] - bf2f(b));
      }
      hhi[c] = th; hlo[c] = tl;
    }

    // ---- phase A MFMAs ----
    f32x4 az = {0.f, 0.f, 0.f, 0.f}, ar = {0.f, 0.f, 0.f, 0.f}, ah = {0.f, 0.f, 0.f, 0.f};
#pragma unroll
    for (int c = 0; c < 4; ++c) {
      az = __builtin_amdgcn_mfma_f32_16x16x32_bf16(hhi[c], uzh[c], az, 0, 0, 0);
      az = __builtin_amdgcn_mfma_f32_16x16x32_bf16(hlo[c], uzh[c], az, 0, 0, 0);
      az = __builtin_amdgcn_mfma_f32_16x16x32_bf16(hhi[c], uzl[c], az, 0, 0, 0);
      az = __builtin_amdgcn_mfma_f32_16x16x32_bf16(xa[c],  wzf[c], az, 0, 0, 0);
      ar = __builtin_amdgcn_mfma_f32_16x16x32_bf16(hhi[c], urh[c], ar, 0, 0, 0);
      ar = __builtin_amdgcn_mfma_f32_16x16x32_bf16(hlo[c], urh[c], ar, 0, 0, 0);
      ar = __builtin_amdgcn_mfma_f32_16x16x32_bf16(hhi[c], url[c], ar, 0, 0, 0);
      ar = __builtin_amdgcn_mfma_f32_16x16x32_bf16(xa[c],  wrf[c], ar, 0, 0, 0);
      ah = __builtin_amdgcn_mfma_f32_16x16x32_bf16(xa[c],  whf[c], ah, 0, 0, 0);
    }

    // ---- reduce z,r partials across the 4 K-split waves ----
    __syncthreads();
    *(f32x4*)&scratch[wv][0][sco] = az;
    *(f32x4*)&scratch[wv][1][sco] = ar;
    __syncthreads();
    f32x4 zs = {0, 0, 0, 0}, rs = {0, 0, 0, 0};
#pragma unroll
    for (int w2 = 0; w2 < NWAVE; ++w2) {
      zs += *(const f32x4*)&scratch[w2][0][sco];
      rs += *(const f32x4*)&scratch[w2][1][sco];
    }

    float zv[4], rv[4];
#pragma unroll
    for (int i = 0; i < 4; ++i) {
      zv[i] = 1.f / (1.f + __expf(-(zs[i] + bzv)));
      rv[i] = 1.f / (1.f + __expf(-(rs[i] + brv)));
    }

    if (wv == 0) {
      float* rdst = rbuf + (size_t)g * 16 * GDOUT;
#pragma unroll
      for (int i = 0; i < 4; ++i) {
        const int row = quad * 4 + i;
        cstore1(&rdst[row * GDOUT + jb + col], rv[i]);   // write-through to L3
      }
    }
    __syncthreads();                                 // scratch WAR for phase B
    if (tid == 0) {                                  // release r-slice: drain + sc1 atomic
      vm_drain();
      __hip_atomic_fetch_add(rcnt, 1u, __ATOMIC_RELAXED, __HIP_MEMORY_SCOPE_AGENT);
    }

    // ---- wait for full r(t) ----
    if (lane == 0) {
      const uint32_t tgt = (uint32_t)(NP * (t + 1));
      int it = 0;
      while (__hip_atomic_load(rcnt, __ATOMIC_RELAXED, __HIP_MEMORY_SCOPE_AGENT) < tgt) {
        __builtin_amdgcn_s_sleep(1);
        if (++it > 200000) break;
      }
    }
    asm volatile("" ::: "memory");

    // ---- phase B: ah += (r .* h) @ Uh  (hi/lo split) ----
    f32x4 r0a[4], r1a[4];
    cload_slab(rbuf + (size_t)g * 16 * GDOUT + col * GDOUT + kb + quad * 8, r0a, r1a);
#pragma unroll
    for (int c = 0; c < 4; ++c) {
      bf16x8 th, tl;
#pragma unroll
      for (int i = 0; i < 4; ++i) {
        float v0 = r0a[c][i] * hf0[c][i];
        float v1 = r1a[c][i] * hf1[c][i];
        short a = f2bf(v0); th[i] = a;     tl[i] = f2bf(v0 - bf2f(a));
        short b = f2bf(v1); th[i + 4] = b; tl[i + 4] = f2bf(v1 - bf2f(b));
      }
      ah = __builtin_amdgcn_mfma_f32_16x16x32_bf16(th, uhh[c], ah, 0, 0, 0);
      ah = __builtin_amdgcn_mfma_f32_16x16x32_bf16(tl, uhh[c], ah, 0, 0, 0);
      ah = __builtin_amdgcn_mfma_f32_16x16x32_bf16(th, uhl[c], ah, 0, 0, 0);
    }

    *(f32x4*)&scratch[wv][0][sco] = ah;
    __syncthreads();
    if (wv == 0) {
      f32x4 hs = {0, 0, 0, 0};
#pragma unroll
      for (int w2 = 0; w2 < NWAVE; ++w2)
        hs += *(const f32x4*)&scratch[w2][0][sco];
#pragma unroll
      for (int i = 0; i < 4; ++i) {
        const int row = quad * 4 + i;
        const float pre = hs[i] + bhv;
        const float e = __expf(2.f * pre);           // tanh, saturation-safe
        const float hh = 1.f - 2.f / (e + 1.f);
        float hn = zv[i] * hreg[i] + (1.f - zv[i]) * hh;
        hn = (mk[i] > 0) ? hn : hreg[i];
        hreg[i] = hn;
        cstore1(&hdst[row * GDOUT + jb + col], hn);
        if (t == GT - 1) out[(16 * g + row) * GDOUT + jb + col] = hn;
      }
    }
    if (tid == 0) {                                  // release h(t+1)
      vm_drain();
      __hip_atomic_fetch_add(hcnt, 1u, __ATOMIC_RELAXED, __HIP_MEMORY_SCOPE_AGENT);
    }
  }
}

extern "C" void kernel_launch(void* const* d_in, const int* in_sizes, int n_in,
                              void* d_out, int out_size, void* d_ws, size_t ws_size,
                              hipStream_t stream) {
  const float* X  = (const float*)d_in[0];
  const int* mask = (const int*)d_in[1];
  const float* Wz = (const float*)d_in[2];
  const float* Uz = (const float*)d_in[3];
  const float* bz = (const float*)d_in[4];
  const float* Wr = (const float*)d_in[5];
  const float* Ur = (const float*)d_in[6];
  const float* br = (const float*)d_in[7];
  const float* Wh = (const float*)d_in[8];
  const float* Uh = (const float*)d_in[9];
  const float* bh = (const float*)d_in[10];

  // zero h0, rbuf, and sync counters (d_ws is re-poisoned 0xAA before every launch)
  const size_t initBytes = (size_t)(2 * NGRP + NGRP) * 16 * GDOUT * 4 + 4096;
  hipMemsetAsync(d_ws, 0, initBytes, stream);

  hipLaunchKernelGGL(gru_fused, dim3(NGRP * NP), dim3(256), 0, stream,
                     X, mask, Wz, Uz, bz, Wr, Ur, br, Wh, Uh, bh,
                     (float*)d_out, (float*)d_ws);
}

// Round 3
// 3539.826 us; speedup vs baseline: 3.7465x; 1.2728x over previous
//
#include <hip/hip_runtime.h>
#include <stdint.h>

// GRU fused persistent kernel, MI355X gfx950 — round 3.
// r1: __threadfence = full L2 wbinv -> 13.3ms. r2: sc0/sc1 exchange, relaxed
// agent counter -> 4.5ms. r2 residual: per-phase sync ~3.5us = 32 serialized
// atomicAdd RMWs on ONE counter + whole-group (32-producer) waits.
// r3: (a) per-WG monotone FLAGS (plain sc0sc1 store after vmcnt(0) drain; no
// RMW, 32 parallel stores); (b) each wave polls only ITS 8 k-slice producers,
// lane-parallel (lane&7 gather + __all), so MFMAs start as soon as the wave's
// own operands are published; (c) scratch-WAR barrier moved after the phase-B
// poll so waves don't idle behind wv0's release stores; z/r reduce wv0-only.
//
// Structure: 4 batch-groups (M=16) x 32 WGs (j-slice 16) = 128 blocks
// co-resident; 4 waves K-split 128 + LDS reduce; weights as register B-frags
// (hi/lo bf16 split on U_* => fp32-grade recurrence, absmax 7.8e-3 passes);
// X projections fused, X read once, issued before the h-wait.
//
// ws (floats): hbuf[2][4][16][512] | rbuf[4][16][512] | hflag[4][32]x32u32 |
//              rflag[4][32]x32u32   (flags cacheline-strided, monotone t+1)
// Sync-safety sketch: wave wv of WG P waits hflag>=t on pg=8wv..8wv+7; the
// phase-A reduce barrier joins all 4 waves => any post-reduce action of P is
// ordered after ALL 32 WGs finished step t-1. r(t+1) overwrite and h parity-
// buffer overwrite both sit behind such all-32 chains (see r1/r2 analysis).

#define GT    512
#define GDIN  512
#define GDOUT 512
#define NGRP  4
#define NP    32
#define JS    16
#define KW    128
#define NWAVE 4

typedef __attribute__((ext_vector_type(8))) short bf16x8;
typedef __attribute__((ext_vector_type(4))) float f32x4;

__device__ __forceinline__ short f2bf(float f) {
  union { float f; uint32_t u; } v; v.f = f;
  uint32_t r = (v.u + 0x7FFFu + ((v.u >> 16) & 1u)) >> 16;  // RNE
  return (short)(uint16_t)r;
}
__device__ __forceinline__ float bf2f(short s) {
  union { uint32_t u; float f; } v; v.u = ((uint32_t)(uint16_t)s) << 16;
  return v.f;
}

// coherent (L3-level) scalar stores, no cache pollution, no fence
__device__ __forceinline__ void cstore1(float* p, float v) {
  asm volatile("global_store_dword %0, %1, off sc0 sc1" :: "v"(p), "v"(v) : "memory");
}
__device__ __forceinline__ void cstore_u32(uint32_t* p, uint32_t v) {
  asm volatile("global_store_dword %0, %1, off sc0 sc1" :: "v"(p), "v"(v) : "memory");
}
__device__ __forceinline__ void vm_drain() {
  asm volatile("s_waitcnt vmcnt(0)" ::: "memory");
}

// 8x dwordx4 coherent loads (one waitcnt): the wave's 16x32-float A slab.
__device__ __forceinline__ void cload_slab(const float* base, f32x4 d0[4], f32x4 d1[4]) {
  asm volatile(
    "global_load_dwordx4 %0, %8, off sc0 sc1\n\t"
    "global_load_dwordx4 %1, %8, off offset:16 sc0 sc1\n\t"
    "global_load_dwordx4 %2, %8, off offset:128 sc0 sc1\n\t"
    "global_load_dwordx4 %3, %8, off offset:144 sc0 sc1\n\t"
    "global_load_dwordx4 %4, %8, off offset:256 sc0 sc1\n\t"
    "global_load_dwordx4 %5, %8, off offset:272 sc0 sc1\n\t"
    "global_load_dwordx4 %6, %8, off offset:384 sc0 sc1\n\t"
    "global_load_dwordx4 %7, %8, off offset:400 sc0 sc1\n\t"
    "s_waitcnt vmcnt(0)"
    : "=&v"(d0[0]), "=&v"(d1[0]), "=&v"(d0[1]), "=&v"(d1[1]),
      "=&v"(d0[2]), "=&v"(d1[2]), "=&v"(d0[3]), "=&v"(d1[3])
    : "v"(base)
    : "memory");
}

// Wave polls 8 producer flags (pg = pgBase + lane&7), lane-parallel.
__device__ __forceinline__ void wait8(uint32_t* base, uint32_t tgt, int lane) {
  uint32_t* p = base + (size_t)(lane & 7) * 32;   // 128B-strided flags
  int it = 0;
  for (;;) {
    uint32_t v = __hip_atomic_load(p, __ATOMIC_RELAXED, __HIP_MEMORY_SCOPE_AGENT);
    if (__all((int)(v >= tgt))) break;
    if (++it > 4000000) break;                     // bounded: fail loud, not hang
  }
  asm volatile("" ::: "memory");
}

__global__ __launch_bounds__(256, 1)
void gru_fused(const float* __restrict__ X, const int* __restrict__ mask,
               const float* __restrict__ Wz, const float* __restrict__ Uz,
               const float* __restrict__ bz,
               const float* __restrict__ Wr, const float* __restrict__ Ur,
               const float* __restrict__ br,
               const float* __restrict__ Wh, const float* __restrict__ Uh,
               const float* __restrict__ bh,
               float* __restrict__ out, float* __restrict__ ws)
{
  const int p    = blockIdx.x;
  const int g    = p & (NGRP - 1);      // group spans 2 XCDs (p%8 = g / g+4)
  const int pg   = p >> 2;              // j-slice 0..31
  const int jb   = pg * JS;
  const int tid  = threadIdx.x;
  const int wv   = tid >> 6;
  const int lane = tid & 63;
  const int col  = lane & 15;
  const int quad = lane >> 4;
  const int kb   = wv * KW;

  float* hbuf = ws;                                 // [2][NGRP][16][512]
  float* rbuf = ws + 2 * NGRP * 16 * GDOUT;         // [NGRP][16][512]
  uint32_t* flags = (uint32_t*)(rbuf + NGRP * 16 * GDOUT);
  uint32_t* hflag_g = flags + (size_t)g * NP * 32;            // [32]x32-stride
  uint32_t* rflag_g = flags + 4096 + (size_t)g * NP * 32;
  uint32_t* hflag_my = hflag_g + (size_t)pg * 32;
  uint32_t* rflag_my = rflag_g + (size_t)pg * 32;
  uint32_t* hflag_wv = hflag_g + (size_t)wv * 8 * 32;         // my wave's 8 producers
  uint32_t* rflag_wv = rflag_g + (size_t)wv * 8 * 32;

  __shared__ __align__(16) float scratch[NWAVE][2][320];

  // ---------- one-time: weight B-fragments into registers ----------
  bf16x8 uzh[4], uzl[4], urh[4], url[4], uhh[4], uhl[4];
  bf16x8 wzf[4], wrf[4], whf[4];
#pragma unroll
  for (int c = 0; c < 4; ++c) {
    const int k0 = kb + c * 32 + quad * 8;
    bf16x8 t_uzh, t_uzl, t_urh, t_url, t_uhh, t_uhl, t_wz, t_wr, t_wh;
#pragma unroll
    for (int i = 0; i < 8; ++i) {
      const int idx = (k0 + i) * GDOUT + jb + col;
      float u; short hi;
      u = Uz[idx]; hi = f2bf(u); t_uzh[i] = hi; t_uzl[i] = f2bf(u - bf2f(hi));
      u = Ur[idx]; hi = f2bf(u); t_urh[i] = hi; t_url[i] = f2bf(u - bf2f(hi));
      u = Uh[idx]; hi = f2bf(u); t_uhh[i] = hi; t_uhl[i] = f2bf(u - bf2f(hi));
      t_wz[i] = f2bf(Wz[idx]);
      t_wr[i] = f2bf(Wr[idx]);
      t_wh[i] = f2bf(Wh[idx]);
    }
    uzh[c] = t_uzh; uzl[c] = t_uzl; urh[c] = t_urh; url[c] = t_url;
    uhh[c] = t_uhh; uhl[c] = t_uhl; wzf[c] = t_wz; wrf[c] = t_wr; whf[c] = t_wh;
  }
  const float bzv = bz[jb + col];
  const float brv = br[jb + col];
  const float bhv = bh[jb + col];

  const int sco = col * 20 + quad * 4;

  float hreg[4] = {0.f, 0.f, 0.f, 0.f};   // wv0: my 4 h values (epilogue reuse)

  for (int t = 0; t < GT; ++t) {
    // ---- pre-wait: X fragments + mask for step t (sync-independent) ----
    bf16x8 xa[4];
#pragma unroll
    for (int c = 0; c < 4; ++c) {
      const int k0 = kb + c * 32 + quad * 8;
      const float* xp = X + ((size_t)(16 * g + col) * GT + t) * GDIN + k0;
      f32x4 x0 = *(const f32x4*)xp;
      f32x4 x1 = *(const f32x4*)(xp + 4);
      bf16x8 xf;
#pragma unroll
      for (int i = 0; i < 4; ++i) { xf[i] = f2bf(x0[i]); xf[i + 4] = f2bf(x1[i]); }
      xa[c] = xf;
    }
    int mk[4];
    if (wv == 0) {
#pragma unroll
      for (int i = 0; i < 4; ++i)
        mk[i] = mask[(16 * g + quad * 4 + i) * GT + t];
    }

    // ---- wait for MY wave's 8 h-producers (flag >= t) ----
    if (t) wait8(hflag_wv, (uint32_t)t, lane);

    const float* hsrc = hbuf + ((size_t)(t & 1) * NGRP + g) * 16 * GDOUT;
    float*       hdst = hbuf + ((size_t)((t + 1) & 1) * NGRP + g) * 16 * GDOUT;

    // ---- h A-slab: 8 pipelined coherent 16B loads, then bf16 hi/lo split ----
    f32x4 hf0[4], hf1[4];
    cload_slab(hsrc + col * GDOUT + kb + quad * 8, hf0, hf1);
    bf16x8 hhi[4], hlo[4];
#pragma unroll
    for (int c = 0; c < 4; ++c) {
      bf16x8 th, tl;
#pragma unroll
      for (int i = 0; i < 4; ++i) {
        short a = f2bf(hf0[c][i]); th[i] = a;     tl[i] = f2bf(hf0[c][i] - bf2f(a));
        short b = f2bf(hf1[c][i]); th[i + 4] = b; tl[i + 4] = f2bf(hf1[c][i] - bf2f(b));
      }
      hhi[c] = th; hlo[c] = tl;
    }

    // ---- phase A MFMAs ----
    f32x4 az = {0.f, 0.f, 0.f, 0.f}, ar = {0.f, 0.f, 0.f, 0.f}, ah = {0.f, 0.f, 0.f, 0.f};
#pragma unroll
    for (int c = 0; c < 4; ++c) {
      az = __builtin_amdgcn_mfma_f32_16x16x32_bf16(hhi[c], uzh[c], az, 0, 0, 0);
      az = __builtin_amdgcn_mfma_f32_16x16x32_bf16(hlo[c], uzh[c], az, 0, 0, 0);
      az = __builtin_amdgcn_mfma_f32_16x16x32_bf16(hhi[c], uzl[c], az, 0, 0, 0);
      az = __builtin_amdgcn_mfma_f32_16x16x32_bf16(xa[c],  wzf[c], az, 0, 0, 0);
      ar = __builtin_amdgcn_mfma_f32_16x16x32_bf16(hhi[c], urh[c], ar, 0, 0, 0);
      ar = __builtin_amdgcn_mfma_f32_16x16x32_bf16(hlo[c], urh[c], ar, 0, 0, 0);
      ar = __builtin_amdgcn_mfma_f32_16x16x32_bf16(hhi[c], url[c], ar, 0, 0, 0);
      ar = __builtin_amdgcn_mfma_f32_16x16x32_bf16(xa[c],  wrf[c], ar, 0, 0, 0);
      ah = __builtin_amdgcn_mfma_f32_16x16x32_bf16(xa[c],  whf[c], ah, 0, 0, 0);
    }

    // ---- publish z,r partials; wv0 reduces + releases r ----
    __syncthreads();                    // WAR: prev step's wv0 epilogue read done
    *(f32x4*)&scratch[wv][0][sco] = az;
    *(f32x4*)&scratch[wv][1][sco] = ar;
    __syncthreads();

    float zv[4];
    if (wv == 0) {
      f32x4 zs = {0, 0, 0, 0}, rs = {0, 0, 0, 0};
#pragma unroll
      for (int w2 = 0; w2 < NWAVE; ++w2) {
        zs += *(const f32x4*)&scratch[w2][0][sco];
        rs += *(const f32x4*)&scratch[w2][1][sco];
      }
      float* rdst = rbuf + (size_t)g * 16 * GDOUT;
#pragma unroll
      for (int i = 0; i < 4; ++i) {
        zv[i] = 1.f / (1.f + __expf(-(zs[i] + bzv)));
        float rv = 1.f / (1.f + __expf(-(rs[i] + brv)));
        cstore1(&rdst[(quad * 4 + i) * GDOUT + jb + col], rv);
      }
      vm_drain();                       // r-slice visible at L3
      if (lane == 0) cstore_u32(rflag_my, (uint32_t)(t + 1));   // release
    }

    // ---- wait for MY wave's 8 r-producers, load, phase B MFMAs ----
    wait8(rflag_wv, (uint32_t)(t + 1), lane);
    f32x4 r0a[4], r1a[4];
    cload_slab(rbuf + (size_t)g * 16 * GDOUT + col * GDOUT + kb + quad * 8, r0a, r1a);
#pragma unroll
    for (int c = 0; c < 4; ++c) {
      bf16x8 th, tl;
#pragma unroll
      for (int i = 0; i < 4; ++i) {
        float v0 = r0a[c][i] * hf0[c][i];
        float v1 = r1a[c][i] * hf1[c][i];
        short a = f2bf(v0); th[i] = a;     tl[i] = f2bf(v0 - bf2f(a));
        short b = f2bf(v1); th[i + 4] = b; tl[i + 4] = f2bf(v1 - bf2f(b));
      }
      ah = __builtin_amdgcn_mfma_f32_16x16x32_bf16(th, uhh[c], ah, 0, 0, 0);
      ah = __builtin_amdgcn_mfma_f32_16x16x32_bf16(tl, uhh[c], ah, 0, 0, 0);
      ah = __builtin_amdgcn_mfma_f32_16x16x32_bf16(th, uhl[c], ah, 0, 0, 0);
    }

    __syncthreads();                    // WAR: wv0's z/r reduce read done
    *(f32x4*)&scratch[wv][0][sco] = ah;
    __syncthreads();

    if (wv == 0) {
      f32x4 hs = {0, 0, 0, 0};
#pragma unroll
      for (int w2 = 0; w2 < NWAVE; ++w2)
        hs += *(const f32x4*)&scratch[w2][0][sco];
#pragma unroll
      for (int i = 0; i < 4; ++i) {
        const int row = quad * 4 + i;
        const float pre = hs[i] + bhv;
        const float e = __expf(2.f * pre);       // tanh, saturation-safe
        const float hh = 1.f - 2.f / (e + 1.f);
        float hn = zv[i] * hreg[i] + (1.f - zv[i]) * hh;
        hn = (mk[i] > 0) ? hn : hreg[i];
        hreg[i] = hn;
        cstore1(&hdst[row * GDOUT + jb + col], hn);
        if (t == GT - 1) out[(16 * g + row) * GDOUT + jb + col] = hn;
      }
      vm_drain();                       // h-slice visible at L3
      if (lane == 0) cstore_u32(hflag_my, (uint32_t)(t + 1));   // release h(t+1)
    }
  }
}

extern "C" void kernel_launch(void* const* d_in, const int* in_sizes, int n_in,
                              void* d_out, int out_size, void* d_ws, size_t ws_size,
                              hipStream_t stream) {
  const float* X  = (const float*)d_in[0];
  const int* mask = (const int*)d_in[1];
  const float* Wz = (const float*)d_in[2];
  const float* Uz = (const float*)d_in[3];
  const float* bz = (const float*)d_in[4];
  const float* Wr = (const float*)d_in[5];
  const float* Ur = (const float*)d_in[6];
  const float* br = (const float*)d_in[7];
  const float* Wh = (const float*)d_in[8];
  const float* Uh = (const float*)d_in[9];
  const float* bh = (const float*)d_in[10];

  // zero h0, rbuf, flags (d_ws re-poisoned 0xAA before every launch)
  const size_t initBytes = (size_t)(2 * NGRP + NGRP) * 16 * GDOUT * 4  // h+r bufs
                         + 2 * 4096 * 4;                                // flags
  hipMemsetAsync(d_ws, 0, initBytes, stream);

  hipLaunchKernelGGL(gru_fused, dim3(NGRP * NP), dim3(256), 0, stream,
                     X, mask, Wz, Uz, bz, Wr, Ur, br, Wh, Uh, bh,
                     (float*)d_out, (float*)d_ws);
}